// Round 1
// baseline (240.781 us; speedup 1.0000x reference)
//
#include <hip/hip_runtime.h>
#include <math.h>

#define BATCH 4
#define NSEQ 4096
#define DM 256
#define BLK 64
#define NB 64
#define TOPK 4
#define DPAD 260   // S / V row stride: %32==4 (bank spread), *4 %16==0 (float4 aligned)
#define DCH 128    // D-chunk for Q/K staging
#define DCHP 132   // chunk row stride, same properties

// ---------------- kernel 1: per-block centroids of q and k ----------------
__global__ void centroid_kernel(const float* __restrict__ q, const float* __restrict__ k,
                                float* __restrict__ qc, float* __restrict__ kc) {
    const int blk = blockIdx.x;          // b*NB + block index
    const int d = threadIdx.x;           // 0..255
    const float* qp = q + (size_t)blk * BLK * DM + d;
    const float* kp = k + (size_t)blk * BLK * DM + d;
    float sq = 0.f, sk = 0.f;
#pragma unroll
    for (int r = 0; r < BLK; ++r) {
        sq += qp[(size_t)r * DM];
        sk += kp[(size_t)r * DM];
    }
    qc[(size_t)blk * DM + d] = sq * (1.0f / BLK);
    kc[(size_t)blk * DM + d] = sk * (1.0f / BLK);
}

// ---------------- kernel 2: centroid distances + top-4 (smallest) ----------------
__global__ void topk_kernel(const float* __restrict__ qc, const float* __restrict__ kc,
                            int* __restrict__ top4) {
    const int b = blockIdx.x / NB;
    const int j = threadIdx.x;           // candidate k-block, 0..63 (one wave)
    const float* qcp = qc + (size_t)blockIdx.x * DM;
    const float* kcp = kc + ((size_t)b * NB + j) * DM;
    float s = 0.f;
    for (int d = 0; d < DM; ++d) {
        float diff = qcp[d] - kcp[d];
        s += diff * diff;
    }
    float dist = sqrtf(s);               // sqrt like reference (tie semantics)
    for (int t = 0; t < TOPK; ++t) {
        float mv = dist;
        int mi = j;
#pragma unroll
        for (int off = 32; off >= 1; off >>= 1) {
            float ov = __shfl_xor(mv, off);
            int oi = __shfl_xor(mi, off);
            if (ov < mv || (ov == mv && oi < mi)) { mv = ov; mi = oi; }  // stable: lower idx wins ties
        }
        if (j == 0) top4[(size_t)blockIdx.x * TOPK + t] = mi;
        if (j == mi) dist = INFINITY;
    }
}

// ---------------- kernel 3: block-sparse attention, one q-block per CU ----------------
__global__ __launch_bounds__(256, 1)
void attn_kernel(const float* __restrict__ q, const float* __restrict__ k,
                 const float* __restrict__ v, const int* __restrict__ top4,
                 float* __restrict__ out) {
    extern __shared__ float lds[];
    float* Ssm = lds;                    // [64][DPAD] scores -> probs
    float* Qs  = lds + 64 * DPAD;        // [64][DCHP] q chunk
    float* Ks  = Qs + 64 * DCHP;         // [64][DCHP] k chunk
    float* Vs  = lds + 64 * DPAD;        // [64][DPAD] aliases Qs/Ks (PV phase)

    const int b  = blockIdx.x / NB;
    const int qb = blockIdx.x % NB;
    const int tid = threadIdx.x;
    const int tx = tid & 15;             // j / d group
    const int ty = tid >> 4;             // i group (0..15)

    int sel[TOPK];
#pragma unroll
    for (int t = 0; t < TOPK; ++t) sel[t] = top4[(size_t)blockIdx.x * TOPK + t];

    const float* qbase = q + ((size_t)b * NSEQ + (size_t)qb * BLK) * DM;

    float acc[TOPK][16];                 // QK accumulators: 4 kb tiles x (4i x 4j)
#pragma unroll
    for (int t = 0; t < TOPK; ++t)
#pragma unroll
        for (int e = 0; e < 16; ++e) acc[t][e] = 0.f;

    // ---- QK^T: loop D in 2 chunks of 128; per chunk loop the 4 selected k-blocks ----
    for (int dc = 0; dc < 2; ++dc) {
        __syncthreads();                 // prior readers of Qs done
#pragma unroll
        for (int it = 0; it < 8; ++it) { // stage Q chunk: 64x128, coalesced float4
            int li = tid + it * 256;
            int row = li >> 5;
            int c4 = (li & 31) << 2;
            *(float4*)(Qs + row * DCHP + c4) =
                *(const float4*)(qbase + (size_t)row * DM + dc * DCH + c4);
        }
        for (int kb = 0; kb < TOPK; ++kb) {
            __syncthreads();             // prior readers of Ks done (also publishes Qs)
            const float* kbase = k + ((size_t)b * NSEQ + (size_t)sel[kb] * BLK) * DM;
#pragma unroll
            for (int it = 0; it < 8; ++it) {
                int li = tid + it * 256;
                int row = li >> 5;
                int c4 = (li & 31) << 2;
                *(float4*)(Ks + row * DCHP + c4) =
                    *(const float4*)(kbase + (size_t)row * DM + dc * DCH + c4);
            }
            __syncthreads();
            // i = ty + 16*ii, j = tx + 16*jj  (strided maps -> conflict-free LDS reads)
            for (int d4 = 0; d4 < DCH; d4 += 4) {
                float4 qv[4], kv[4];
#pragma unroll
                for (int ii = 0; ii < 4; ++ii)
                    qv[ii] = *(const float4*)(Qs + (ty + 16 * ii) * DCHP + d4);
#pragma unroll
                for (int jj = 0; jj < 4; ++jj)
                    kv[jj] = *(const float4*)(Ks + (tx + 16 * jj) * DCHP + d4);
#pragma unroll
                for (int ii = 0; ii < 4; ++ii)
#pragma unroll
                    for (int jj = 0; jj < 4; ++jj)
                        acc[kb][ii * 4 + jj] += qv[ii].x * kv[jj].x + qv[ii].y * kv[jj].y +
                                                qv[ii].z * kv[jj].z + qv[ii].w * kv[jj].w;
            }
        }
    }

    // ---- scores -> LDS (scaled) ----
    const float scale = 0.0625f;         // 1/sqrt(256)
#pragma unroll
    for (int kb = 0; kb < TOPK; ++kb)
#pragma unroll
        for (int ii = 0; ii < 4; ++ii)
#pragma unroll
            for (int jj = 0; jj < 4; ++jj)
                Ssm[(ty + 16 * ii) * DPAD + kb * 64 + tx + 16 * jj] = acc[kb][ii * 4 + jj] * scale;
    __syncthreads();

    // ---- softmax over 256 gathered columns (all valid; mask keeps whole blocks) ----
    {
        const int lane = tid & 63;
        const int w = tid >> 6;          // wave id 0..3, 16 rows each
        for (int rr = 0; rr < 16; ++rr) {
            const int r = w * 16 + rr;
            float4 sv = *(float4*)(Ssm + r * DPAD + lane * 4);
            float m = fmaxf(fmaxf(sv.x, sv.y), fmaxf(sv.z, sv.w));
#pragma unroll
            for (int off = 32; off >= 1; off >>= 1) m = fmaxf(m, __shfl_xor(m, off));
            sv.x = __expf(sv.x - m);
            sv.y = __expf(sv.y - m);
            sv.z = __expf(sv.z - m);
            sv.w = __expf(sv.w - m);
            float ssum = sv.x + sv.y + sv.z + sv.w;
#pragma unroll
            for (int off = 32; off >= 1; off >>= 1) ssum += __shfl_xor(ssum, off);
            const float inv = 1.0f / ssum;
            sv.x *= inv; sv.y *= inv; sv.z *= inv; sv.w *= inv;
            *(float4*)(Ssm + r * DPAD + lane * 4) = sv;
        }
    }
    __syncthreads();                     // probs visible; Qs/Ks readers long done -> Vs may overwrite

    // ---- PV: thread owns i = ty*4+ii (4 rows) x d = tx*4 + 64*c (+e) (16 cols) ----
    float4 o[4][4];
#pragma unroll
    for (int ii = 0; ii < 4; ++ii)
#pragma unroll
        for (int c = 0; c < 4; ++c) o[ii][c] = make_float4(0.f, 0.f, 0.f, 0.f);

    for (int kb = 0; kb < TOPK; ++kb) {
        if (kb) __syncthreads();         // prior Vs readers done
        const float* vbase = v + ((size_t)b * NSEQ + (size_t)sel[kb] * BLK) * DM;
#pragma unroll
        for (int it = 0; it < 16; ++it) {// stage V block: 64x256, coalesced float4
            int li = tid + it * 256;
            int row = li >> 6;
            int c4 = (li & 63) << 2;
            *(float4*)(Vs + row * DPAD + c4) = *(const float4*)(vbase + (size_t)row * DM + c4);
        }
        __syncthreads();
        for (int j = 0; j < BLK; ++j) {
            float p[4];
#pragma unroll
            for (int ii = 0; ii < 4; ++ii) p[ii] = Ssm[(ty * 4 + ii) * DPAD + kb * 64 + j];
#pragma unroll
            for (int c = 0; c < 4; ++c) {
                float4 vv = *(const float4*)(Vs + j * DPAD + tx * 4 + 64 * c);
#pragma unroll
                for (int ii = 0; ii < 4; ++ii) {
                    o[ii][c].x += p[ii] * vv.x;
                    o[ii][c].y += p[ii] * vv.y;
                    o[ii][c].z += p[ii] * vv.z;
                    o[ii][c].w += p[ii] * vv.w;
                }
            }
        }
    }

    float* obase = out + ((size_t)b * NSEQ + (size_t)qb * BLK) * DM;
#pragma unroll
    for (int ii = 0; ii < 4; ++ii)
#pragma unroll
        for (int c = 0; c < 4; ++c)
            *(float4*)(obase + (size_t)(ty * 4 + ii) * DM + tx * 4 + 64 * c) = o[ii][c];
}

extern "C" void kernel_launch(void* const* d_in, const int* in_sizes, int n_in,
                              void* d_out, int out_size, void* d_ws, size_t ws_size,
                              hipStream_t stream) {
    const float* q = (const float*)d_in[0];
    const float* k = (const float*)d_in[1];
    const float* v = (const float*)d_in[2];
    float* out = (float*)d_out;

    // workspace: qc (64K floats) | kc (64K floats) | top4 (1K ints)  => ~516 KB
    float* qc = (float*)d_ws;
    float* kc = qc + (size_t)BATCH * NB * DM;
    int* top4 = (int*)(kc + (size_t)BATCH * NB * DM);

    centroid_kernel<<<BATCH * NB, DM, 0, stream>>>(q, k, qc, kc);
    topk_kernel<<<BATCH * NB, BLK, 0, stream>>>(qc, kc, top4);

    const int lds_bytes = (64 * DPAD + 2 * 64 * DCHP) * (int)sizeof(float);  // 134144 B
    hipFuncSetAttribute((const void*)attn_kernel,
                        hipFuncAttributeMaxDynamicSharedMemorySize, lds_bytes);
    attn_kernel<<<BATCH * NB, 256, lds_bytes, stream>>>(q, k, v, top4, out);
}

// Round 4
// 135.134 us; speedup vs baseline: 1.7818x; 1.7818x over previous
//
#include <hip/hip_runtime.h>
#include <math.h>
#include <stdint.h>

#define BATCH 4
#define NSEQ 4096
#define DM 256
#define BLK 64
#define NB 64
#define TOPK 4

typedef unsigned short u16;
typedef unsigned int u32;
typedef __attribute__((ext_vector_type(8))) short bf16x8;   // 8 bf16 = 4 VGPR (guide-verified frag type)
typedef __attribute__((ext_vector_type(4))) float f32x4;

__device__ __forceinline__ u16 f2bf(float f) {              // RTNE fp32->bf16 (inputs are finite)
    union { float f; u32 u; } c{f};
    u32 r = c.u + 0x7FFFu + ((c.u >> 16) & 1u);
    return (u16)(r >> 16);
}
__device__ __forceinline__ float bf2f(u16 h) {
    union { u32 u; float f; } c{((u32)h) << 16};
    return c.f;
}

// ---------------- prep: centroids + Q/K bf16 hi/lo split + per-block V transpose (bf16) ----------
__global__ __launch_bounds__(256) void prep_kernel(
    const float* __restrict__ q, const float* __restrict__ k, const float* __restrict__ v,
    u16* __restrict__ qh, u16* __restrict__ ql, u16* __restrict__ kh, u16* __restrict__ kl,
    u16* __restrict__ vtg, float* __restrict__ qc, float* __restrict__ kc)
{
    __shared__ u16 vt[256 * 66];                 // V^T tile staging, 66-pad => conflict-free
    const int gblk = blockIdx.x;                 // b*NB + blk
    const int d = threadIdx.x;                   // 0..255, owns one column
    const size_t base = (size_t)gblk * (BLK * DM);

    float s = 0.f;
#pragma unroll 8
    for (int r = 0; r < BLK; ++r) {              // coalesced per-row reads
        float x = q[base + (size_t)r * DM + d];
        s += x;
        u16 h = f2bf(x);
        qh[base + (size_t)r * DM + d] = h;
        ql[base + (size_t)r * DM + d] = f2bf(x - bf2f(h));
    }
    qc[(size_t)gblk * DM + d] = s * (1.f / BLK);

    s = 0.f;
#pragma unroll 8
    for (int r = 0; r < BLK; ++r) {
        float x = k[base + (size_t)r * DM + d];
        s += x;
        u16 h = f2bf(x);
        kh[base + (size_t)r * DM + d] = h;
        kl[base + (size_t)r * DM + d] = f2bf(x - bf2f(h));
    }
    kc[(size_t)gblk * DM + d] = s * (1.f / BLK);

#pragma unroll 8
    for (int r = 0; r < BLK; ++r)                // vt[d][r] = bf16(V[r][d]); writes conflict-free
        vt[d * 66 + r] = f2bf(v[base + (size_t)r * DM + d]);
    __syncthreads();

    // write vtg[gblk][d][j] (= V[j][d]) : each wave iter handles 2 rows (32 u32 each) —
    // in-bounds, no cross-row overlap (race-fix vs r2), 2-way-bank reads, 256B-coalesced stores
    const int w = threadIdx.x >> 6, lane = threadIdx.x & 63;
    const int half = lane >> 5, c = lane & 31;
    const u32* vts = (const u32*)vt;
    u32* vo = (u32*)vtg + (base >> 1);
#pragma unroll
    for (int i = 0; i < 32; ++i) {
        int dr = w * 64 + i * 2 + half;
        vo[dr * 32 + c] = vts[dr * 33 + c];
    }
}

// ---------------- topk: LDS-staged centroid distances + stable top-4 ----------------
__global__ __launch_bounds__(256) void topk_kernel(const float* __restrict__ qc,
                                                   const float* __restrict__ kc,
                                                   int* __restrict__ top4)
{
    extern __shared__ float kcl[];               // [64][258] + red[256]
    float* red = kcl + 64 * 258;
    const int bid = blockIdx.x;
    const int swz = (bid & 7) * 32 + (bid >> 3); // XCD-locality swizzle (bijective, 256%8==0)
    const int b = swz >> 6;
    const int t = threadIdx.x;

    const float* kcb = kc + (size_t)(b * NB) * DM;
#pragma unroll
    for (int it = 0; it < 64; ++it) {            // stage 64x256 f32, coalesced, conflict-free (258 pad)
        int li = t + it * 256;
        kcl[(li >> 8) * 258 + (li & 255)] = kcb[li];
    }
    __syncthreads();

    const int j = t & 63, dq = t >> 6;           // wave dq handles a 64-d slice, lane = candidate j
    const float* qrow = qc + (size_t)swz * DM;   // wave-uniform loads (L2-hot)
    float s = 0.f;
#pragma unroll 8
    for (int dd = 0; dd < 64; ++dd) {
        float diff = qrow[dq * 64 + dd] - kcl[j * 258 + dq * 64 + dd];
        s += diff * diff;
    }
    red[dq * 64 + j] = s;
    __syncthreads();

    if (t < 64) {
        float dist = sqrtf(red[t] + red[64 + t] + red[128 + t] + red[192 + t]);
        for (int sel = 0; sel < TOPK; ++sel) {   // iterative min, lower index wins ties (matches top_k)
            float mv = dist;
            int mi = t;
#pragma unroll
            for (int off = 32; off >= 1; off >>= 1) {
                float ov = __shfl_xor(mv, off);
                int oi = __shfl_xor(mi, off);
                if (ov < mv || (ov == mv && oi < mi)) { mv = ov; mi = oi; }
            }
            if (t == 0) top4[swz * 4 + sel] = mi;
            if (t == mi) dist = 3.0e38f;
        }
    }
}

// ---------------- attn: bf16 MFMA, swapped QK^T (bf16x3), in-reg softmax, PV via V^T ----------
// LDS halfword map (total 67584 hw = 132 KB):
//   QH @ 0      [64][264]  (aliased by P after QK)
//   QL @ 16896  [64][264]
//   KH @ 33792  [64][264]  (aliased by VT [256][72] during PV)
//   KL @ 50688  [64][264]
#define QH_O 0
#define QL_O 16896
#define KH_O 33792
#define KL_O 50688
#define VT_O 33792

__global__ __launch_bounds__(256, 1) void attn_kernel(
    const u16* __restrict__ qh, const u16* __restrict__ ql,
    const u16* __restrict__ kh, const u16* __restrict__ kl,
    const u16* __restrict__ vtg, const int* __restrict__ top4, float* __restrict__ out)
{
    extern __shared__ u16 smem[];
    const int bid = blockIdx.x;
    const int swz = (bid & 7) * 32 + (bid >> 3); // same-batch blocks share an XCD (K/V L2 locality)
    const int b = swz >> 6, qb = swz & 63;
    const int tid = threadIdx.x;
    const int w = tid >> 6, lane = tid & 63;
    const int x = lane & 15, g = lane >> 4;      // frag coords: row sel / k-group

    // 64x256 bf16 tile -> 264-pad LDS (all b128 ops bank-optimal)
    auto stage64 = [&](int dsthw, const u16* __restrict__ src) {
#pragma unroll
        for (int it = 0; it < 8; ++it) {
            int li = tid + it * 256;
            int row = li >> 5, c8 = li & 31;
            *(uint4*)&smem[dsthw + row * 264 + c8 * 8] = *(const uint4*)&src[row * 256 + c8 * 8];
        }
    };
    // 256x64 bf16 V^T tile -> 72-pad LDS
    auto stageVt = [&](const u16* __restrict__ src) {
#pragma unroll
        for (int it = 0; it < 8; ++it) {
            int li = tid + it * 256;
            int dr = li >> 3, c8 = li & 7;
            *(uint4*)&smem[VT_O + dr * 72 + c8 * 8] = *(const uint4*)&src[dr * 64 + c8 * 8];
        }
    };

    int sel[TOPK];
#pragma unroll
    for (int t = 0; t < TOPK; ++t) sel[t] = top4[swz * 4 + t];

    const size_t qbase = (size_t)swz * (BLK * DM);
    stage64(QH_O, qh + qbase);
    stage64(QL_O, ql + qbase);
    {
        size_t kb0 = (size_t)(b * NB + sel[0]) * (BLK * DM);
        stage64(KH_O, kh + kb0);
        stage64(KL_O, kl + kb0);
    }
    __syncthreads();

    // Q B-frags held in regs (B[k=d][n=i]: lane -> i=x (row w*16+x), d=(dc*32+g*8+e)) — reused all kb
    bf16x8 bqh[8], bql[8];
    const int qrow = w * 16 + x;
#pragma unroll
    for (int dc = 0; dc < 8; ++dc) {
        bqh[dc] = *(const bf16x8*)&smem[QH_O + qrow * 264 + dc * 32 + g * 8];
        bql[dc] = *(const bf16x8*)&smem[QL_O + qrow * 264 + dc * 32 + g * 8];
    }

    // S^T accumulators: tile tt = kb*4+jt holds S^T[j=jt*16+g*4+r][i=w*16+x]
    f32x4 S[16];
#pragma unroll
    for (int t = 0; t < 16; ++t) S[t] = (f32x4){0.f, 0.f, 0.f, 0.f};

#pragma unroll
    for (int kb = 0; kb < TOPK; ++kb) {
#pragma unroll
        for (int jt = 0; jt < 4; ++jt) {
            f32x4 acc = S[kb * 4 + jt];
#pragma unroll
            for (int dc = 0; dc < 8; ++dc) {
                // A = K rows (A[m=j][k=d]: lane -> j=x within tile, d=dc*32+g*8+e)
                bf16x8 ah = *(const bf16x8*)&smem[KH_O + (jt * 16 + x) * 264 + dc * 32 + g * 8];
                bf16x8 al = *(const bf16x8*)&smem[KL_O + (jt * 16 + x) * 264 + dc * 32 + g * 8];
                // bf16x3: qh*kh + ql*kh + qh*kl  (ql*kl negligible) => ~fp32-accurate scores
                acc = __builtin_amdgcn_mfma_f32_16x16x32_bf16(ah, bqh[dc], acc, 0, 0, 0);
                acc = __builtin_amdgcn_mfma_f32_16x16x32_bf16(ah, bql[dc], acc, 0, 0, 0);
                acc = __builtin_amdgcn_mfma_f32_16x16x32_bf16(al, bqh[dc], acc, 0, 0, 0);
            }
            S[kb * 4 + jt] = acc;
        }
        __syncthreads();                          // K tile reads done
        if (kb < TOPK - 1) {
            size_t kbn = (size_t)(b * NB + sel[kb + 1]) * (BLK * DM);
            stage64(KH_O, kh + kbn);
            stage64(KL_O, kl + kbn);
            __syncthreads();
        }
    }

    // ---- softmax fully in registers: row i=w*16+x lives in lanes {x, x+16, x+32, x+48} ----
    float mx = -3.0e38f;
#pragma unroll
    for (int t = 0; t < 16; ++t)
#pragma unroll
        for (int r = 0; r < 4; ++r) { S[t][r] *= 0.0625f; mx = fmaxf(mx, S[t][r]); }
    mx = fmaxf(mx, __shfl_xor(mx, 16));
    mx = fmaxf(mx, __shfl_xor(mx, 32));
    float sum = 0.f;
#pragma unroll
    for (int t = 0; t < 16; ++t)
#pragma unroll
        for (int r = 0; r < 4; ++r) { float p = __expf(S[t][r] - mx); S[t][r] = p; sum += p; }
    sum += __shfl_xor(sum, 16);
    sum += __shfl_xor(sum, 32);
    const float inv = 1.f / sum;

    // stage V^T(sel0) into K region (reads done); write P bf16 into Q region (Q-frags in regs)
    stageVt(vtg + (size_t)(b * NB + sel[0]) * (BLK * DM));
    u32* pw = (u32*)smem;                        // P[64][264] @ hw 0, row-major [i][j]
#pragma unroll
    for (int t = 0; t < 16; ++t)
#pragma unroll
        for (int rp = 0; rp < 2; ++rp) {
            u32 dw = (u32)f2bf(S[t][2 * rp] * inv) | ((u32)f2bf(S[t][2 * rp + 1] * inv) << 16);
            pw[qrow * 132 + t * 8 + g * 2 + rp] = dw;   // j = tt*16 + g*4 + {0,1}/{2,3}
        }
    __syncthreads();

    // ---- PV: O[i][d] += P[i][j-chunk] * V^T  (A=P row-major; B lane -> d=dt*16+x, j=jc*32+g*8+e) ----
    f32x4 O[16];
#pragma unroll
    for (int t = 0; t < 16; ++t) O[t] = (f32x4){0.f, 0.f, 0.f, 0.f};

#pragma unroll
    for (int kb = 0; kb < TOPK; ++kb) {
#pragma unroll
        for (int jc = 0; jc < 2; ++jc) {
            bf16x8 pa = *(const bf16x8*)&smem[qrow * 264 + kb * 64 + jc * 32 + g * 8];
#pragma unroll
            for (int dt = 0; dt < 16; ++dt) {
                bf16x8 bv = *(const bf16x8*)&smem[VT_O + (dt * 16 + x) * 72 + jc * 32 + g * 8];
                O[dt] = __builtin_amdgcn_mfma_f32_16x16x32_bf16(pa, bv, O[dt], 0, 0, 0);
            }
        }
        __syncthreads();                          // V tile reads done
        if (kb < TOPK - 1) {
            stageVt(vtg + (size_t)(b * NB + sel[kb + 1]) * (BLK * DM));
            __syncthreads();
        }
    }

    // D layout: row i = w*16 + g*4 + r, col d = dt*16 + x
    float* ob = out + ((size_t)b * NSEQ + (size_t)qb * BLK) * DM;
#pragma unroll
    for (int dt = 0; dt < 16; ++dt)
#pragma unroll
        for (int r = 0; r < 4; ++r)
            ob[(size_t)(w * 16 + g * 4 + r) * DM + dt * 16 + x] = O[dt][r];
}

extern "C" void kernel_launch(void* const* d_in, const int* in_sizes, int n_in,
                              void* d_out, int out_size, void* d_ws, size_t ws_size,
                              hipStream_t stream) {
    const float* q = (const float*)d_in[0];
    const float* k = (const float*)d_in[1];
    const float* v = (const float*)d_in[2];
    float* out = (float*)d_out;

    // ws: qh|ql|kh|kl|vtg (5 x 8.39MB bf16) + qc|kc (2 x 256KB f32) + top4 (4KB) ~= 42.5 MB
    const size_t nelem = (size_t)BATCH * NSEQ * DM;
    u16* qh = (u16*)d_ws;
    u16* ql = qh + nelem;
    u16* kh = ql + nelem;
    u16* kl = kh + nelem;
    u16* vtg = kl + nelem;
    float* qc = (float*)(vtg + nelem);
    float* kc = qc + (size_t)BATCH * NB * DM;
    int* top4 = (int*)(kc + (size_t)BATCH * NB * DM);

    prep_kernel<<<BATCH * NB, 256, 0, stream>>>(q, k, v, qh, ql, kh, kl, vtg, qc, kc);

    const int tk_lds = (64 * 258 + 256) * (int)sizeof(float);   // 67072 B
    hipFuncSetAttribute((const void*)topk_kernel, hipFuncAttributeMaxDynamicSharedMemorySize, tk_lds);
    topk_kernel<<<BATCH * NB, 256, tk_lds, stream>>>(qc, kc, top4);

    const int at_lds = 67584 * 2;                               // 135168 B
    hipFuncSetAttribute((const void*)attn_kernel, hipFuncAttributeMaxDynamicSharedMemorySize, at_lds);
    attn_kernel<<<BATCH * NB, 256, at_lds, stream>>>(qh, ql, kh, kl, vtg, top4, out);
}

// Round 5
// 121.703 us; speedup vs baseline: 1.9784x; 1.1104x over previous
//
#include <hip/hip_runtime.h>
#include <math.h>
#include <stdint.h>

#define BATCH 4
#define NSEQ 4096
#define DM 256
#define BLK 64
#define NB 64
#define TOPK 4

typedef unsigned short u16;
typedef unsigned int u32;
typedef __attribute__((ext_vector_type(8))) _Float16 f16x8;  // 8 f16 = 4 VGPR MFMA frag
typedef __attribute__((ext_vector_type(4))) float f32x4;

__device__ __forceinline__ u16 f2h(float f) {                // fp32->fp16 RTNE (v_cvt_f16_f32)
    union { _Float16 h; u16 u; } c;
    c.h = (_Float16)f;
    return c.u;
}

// ---------------- prep: centroids + Q/K fp16 cast + per-block V transpose (fp16) ----------------
__global__ __launch_bounds__(256) void prep_kernel(
    const float* __restrict__ q, const float* __restrict__ k, const float* __restrict__ v,
    u16* __restrict__ qf, u16* __restrict__ kf, u16* __restrict__ vtg,
    float* __restrict__ qc, float* __restrict__ kc)
{
    __shared__ u16 vt[256 * 66];                 // V^T staging, 66-pad (2-way banks max)
    const int gblk = blockIdx.x;                 // b*NB + blk
    const int d = threadIdx.x;                   // 0..255, owns one column
    const size_t base = (size_t)gblk * (BLK * DM);

    float s = 0.f;
#pragma unroll 8
    for (int r = 0; r < BLK; ++r) {              // coalesced per-row reads
        float x = q[base + (size_t)r * DM + d];
        s += x;
        qf[base + (size_t)r * DM + d] = f2h(x);
    }
    qc[(size_t)gblk * DM + d] = s * (1.f / BLK);

    s = 0.f;
#pragma unroll 8
    for (int r = 0; r < BLK; ++r) {
        float x = k[base + (size_t)r * DM + d];
        s += x;
        kf[base + (size_t)r * DM + d] = f2h(x);
    }
    kc[(size_t)gblk * DM + d] = s * (1.f / BLK);

#pragma unroll 8
    for (int r = 0; r < BLK; ++r)                // vt[d][r] = f16(V[r][d])
        vt[d * 66 + r] = f2h(v[base + (size_t)r * DM + d]);
    __syncthreads();

    // vtg[gblk][d][j] = V[j][d]: 2 rows x 32 u32 per wave-iter (in-bounds, race-free, coalesced)
    const int w = threadIdx.x >> 6, lane = threadIdx.x & 63;
    const int half = lane >> 5, c = lane & 31;
    const u32* vts = (const u32*)vt;
    u32* vo = (u32*)vtg + (base >> 1);
#pragma unroll
    for (int i = 0; i < 32; ++i) {
        int dr = w * 64 + i * 2 + half;
        vo[dr * 32 + c] = vts[dr * 33 + c];
    }
}

// ---------------- topk: LDS-staged centroid distances + stable top-4 (unchanged, passed) --------
__global__ __launch_bounds__(256) void topk_kernel(const float* __restrict__ qc,
                                                   const float* __restrict__ kc,
                                                   int* __restrict__ top4)
{
    extern __shared__ float kcl[];               // [64][258] + red[256]
    float* red = kcl + 64 * 258;
    const int bid = blockIdx.x;
    const int swz = (bid & 7) * 32 + (bid >> 3); // XCD swizzle (bijective, 256%8==0)
    const int b = swz >> 6;
    const int t = threadIdx.x;

    const float* kcb = kc + (size_t)(b * NB) * DM;
#pragma unroll
    for (int it = 0; it < 64; ++it) {
        int li = t + it * 256;
        kcl[(li >> 8) * 258 + (li & 255)] = kcb[li];
    }
    __syncthreads();

    const int j = t & 63, dq = t >> 6;
    const float* qrow = qc + (size_t)swz * DM;
    float s = 0.f;
#pragma unroll 8
    for (int dd = 0; dd < 64; ++dd) {
        float diff = qrow[dq * 64 + dd] - kcl[j * 258 + dq * 64 + dd];
        s += diff * diff;
    }
    red[dq * 64 + j] = s;
    __syncthreads();

    if (t < 64) {
        float dist = sqrtf(red[t] + red[64 + t] + red[128 + t] + red[192 + t]);
        for (int sel = 0; sel < TOPK; ++sel) {   // iterative min, lower index wins ties
            float mv = dist;
            int mi = t;
#pragma unroll
            for (int off = 32; off >= 1; off >>= 1) {
                float ov = __shfl_xor(mv, off);
                int oi = __shfl_xor(mi, off);
                if (ov < mv || (ov == mv && oi < mi)) { mv = ov; mi = oi; }
            }
            if (t == 0) top4[swz * 4 + sel] = mi;
            if (t == mi) dist = 3.0e38f;
        }
    }
}

// ---------------- attn: fp16 MFMA, swapped QK^T, in-reg softmax, PV via swizzled V^T ------------
// LDS halfword map (33792 hw = 67584 B -> 2 WGs/CU):
//   region A @ 0     : Q [64][264]   (aliased by P [64][264] after QK)
//   region B @ 16896 : K [64][264]   (aliased by VT [256][64] XOR-swizzled during PV)
#define KQ_O 16896
#define VT_O 16896

__global__ __launch_bounds__(256, 2) void attn_kernel(
    const u16* __restrict__ qf, const u16* __restrict__ kf,
    const u16* __restrict__ vtg, const int* __restrict__ top4, float* __restrict__ out)
{
    extern __shared__ u16 smem[];
    const int bid = blockIdx.x;
    const int swz = (bid & 7) * 32 + (bid >> 3); // same-batch blocks share an XCD (K/V L2 locality)
    const int b = swz >> 6, qb = swz & 63;
    const int tid = threadIdx.x;
    const int w = tid >> 6, lane = tid & 63;
    const int x = lane & 15, g = lane >> 4;      // frag coords

    // 64x256 f16 tile -> 264-pad LDS (balanced banks, round-4-verified)
    auto stage64 = [&](int dsthw, const u16* __restrict__ src) {
#pragma unroll
        for (int it = 0; it < 8; ++it) {
            int li = tid + it * 256;
            int row = li >> 5, c8 = li & 31;
            *(uint4*)&smem[dsthw + row * 264 + c8 * 8] = *(const uint4*)&src[row * 256 + c8 * 8];
        }
    };
    // 256x64 f16 V^T tile -> pad-free stride 64, XOR chunk-swizzle (chunk ^= row&7): balanced
    auto stageVt = [&](const u16* __restrict__ src) {
#pragma unroll
        for (int it = 0; it < 8; ++it) {
            int li = tid + it * 256;
            int dr = li >> 3, c8 = li & 7;
            *(uint4*)&smem[VT_O + dr * 64 + (c8 ^ (dr & 7)) * 8] = *(const uint4*)&src[dr * 64 + c8 * 8];
        }
    };

    int sel[TOPK];
#pragma unroll
    for (int t = 0; t < TOPK; ++t) sel[t] = top4[swz * 4 + t];

    const size_t qbase = (size_t)swz * (BLK * DM);
    stage64(0, qf + qbase);
    stage64(KQ_O, kf + (size_t)(b * NB + sel[0]) * (BLK * DM));
    __syncthreads();

    // Q B-frags in regs (B[k=d][n=i]: lane -> i=x (row w*16+x), d=dc*32+g*8+e) — reused all kb
    f16x8 bq[8];
    const int qrow = w * 16 + x;
#pragma unroll
    for (int dc = 0; dc < 8; ++dc)
        bq[dc] = *(const f16x8*)&smem[qrow * 264 + dc * 32 + g * 8];

    // S^T accumulators: tile kb*4+jt holds S^T[j=jt*16+g*4+r][i=w*16+x]
    f32x4 S[16];
#pragma unroll
    for (int t = 0; t < 16; ++t) S[t] = (f32x4){0.f, 0.f, 0.f, 0.f};

#pragma unroll
    for (int kb = 0; kb < TOPK; ++kb) {
#pragma unroll
        for (int jt = 0; jt < 4; ++jt) {
            f32x4 acc = S[kb * 4 + jt];
#pragma unroll
            for (int dc = 0; dc < 8; ++dc) {
                // A = K rows (A[m=j][k=d]: lane -> j=jt*16+x, d=dc*32+g*8+e)
                f16x8 ak = *(const f16x8*)&smem[KQ_O + (jt * 16 + x) * 264 + dc * 32 + g * 8];
                acc = __builtin_amdgcn_mfma_f32_16x16x32_f16(ak, bq[dc], acc, 0, 0, 0);
            }
            S[kb * 4 + jt] = acc;
        }
        __syncthreads();                          // K tile reads done
        if (kb < TOPK - 1) {
            stage64(KQ_O, kf + (size_t)(b * NB + sel[kb + 1]) * (BLK * DM));
            __syncthreads();
        }
    }

    // ---- softmax in registers: row i=w*16+x lives in lanes {x, x+16, x+32, x+48} ----
    float mx = -3.0e38f;
#pragma unroll
    for (int t = 0; t < 16; ++t)
#pragma unroll
        for (int r = 0; r < 4; ++r) { S[t][r] *= 0.0625f; mx = fmaxf(mx, S[t][r]); }
    mx = fmaxf(mx, __shfl_xor(mx, 16));
    mx = fmaxf(mx, __shfl_xor(mx, 32));
    float sum = 0.f;
#pragma unroll
    for (int t = 0; t < 16; ++t)
#pragma unroll
        for (int r = 0; r < 4; ++r) { float p = __expf(S[t][r] - mx); S[t][r] = p; sum += p; }
    sum += __shfl_xor(sum, 16);
    sum += __shfl_xor(sum, 32);
    const float inv = 1.f / sum;

    // stage V^T(sel0) into region B (K reads done); write P f16 into region A (Q-frags in regs)
    stageVt(vtg + (size_t)(b * NB + sel[0]) * (BLK * DM));
    u32* pw = (u32*)smem;                        // P[64][264] @ hw 0, row-major [i][j]
#pragma unroll
    for (int t = 0; t < 16; ++t)
#pragma unroll
        for (int rp = 0; rp < 2; ++rp) {
            u32 dw = (u32)f2h(S[t][2 * rp] * inv) | ((u32)f2h(S[t][2 * rp + 1] * inv) << 16);
            pw[qrow * 132 + t * 8 + g * 2 + rp] = dw;   // j = t*16 + g*4 + {0,1}/{2,3}
        }
    __syncthreads();

    // ---- PV: O[i][d] += P[i][j] * V^T[d][j]  (A=P row-major; B lane -> d=dt*16+x, j=jc*32+g*8+e)
    f32x4 O[16];
#pragma unroll
    for (int t = 0; t < 16; ++t) O[t] = (f32x4){0.f, 0.f, 0.f, 0.f};

#pragma unroll
    for (int kb = 0; kb < TOPK; ++kb) {
#pragma unroll
        for (int jc = 0; jc < 2; ++jc) {
            f16x8 pa = *(const f16x8*)&smem[qrow * 264 + kb * 64 + jc * 32 + g * 8];
#pragma unroll
            for (int dt = 0; dt < 16; ++dt) {
                // swizzled read: chunk (jc*4+g) ^ (row&7), row = dt*16+x -> row&7 = x&7
                f16x8 bv = *(const f16x8*)&smem[VT_O + (dt * 16 + x) * 64 + ((jc * 4 + g) ^ (x & 7)) * 8];
                O[dt] = __builtin_amdgcn_mfma_f32_16x16x32_f16(pa, bv, O[dt], 0, 0, 0);
            }
        }
        __syncthreads();                          // V tile reads done
        if (kb < TOPK - 1) {
            stageVt(vtg + (size_t)(b * NB + sel[kb + 1]) * (BLK * DM));
            __syncthreads();
        }
    }

    // D layout: row i = w*16 + g*4 + r, col d = dt*16 + x
    float* ob = out + ((size_t)b * NSEQ + (size_t)qb * BLK) * DM;
#pragma unroll
    for (int dt = 0; dt < 16; ++dt)
#pragma unroll
        for (int r = 0; r < 4; ++r)
            ob[(size_t)(w * 16 + g * 4 + r) * DM + dt * 16 + x] = O[dt][r];
}

extern "C" void kernel_launch(void* const* d_in, const int* in_sizes, int n_in,
                              void* d_out, int out_size, void* d_ws, size_t ws_size,
                              hipStream_t stream) {
    const float* q = (const float*)d_in[0];
    const float* k = (const float*)d_in[1];
    const float* v = (const float*)d_in[2];
    float* out = (float*)d_out;

    // ws: qf|kf|vtg (3 x 8.39MB f16) + qc|kc (2 x 256KB f32) + top4 (4KB) ~= 25.7 MB
    const size_t nelem = (size_t)BATCH * NSEQ * DM;
    u16* qf = (u16*)d_ws;
    u16* kf = qf + nelem;
    u16* vtg = kf + nelem;
    float* qc = (float*)(vtg + nelem);
    float* kc = qc + (size_t)BATCH * NB * DM;
    int* top4 = (int*)(kc + (size_t)BATCH * NB * DM);

    prep_kernel<<<BATCH * NB, 256, 0, stream>>>(q, k, v, qf, kf, vtg, qc, kc);

    const int tk_lds = (64 * 258 + 256) * (int)sizeof(float);   // 67072 B
    hipFuncSetAttribute((const void*)topk_kernel, hipFuncAttributeMaxDynamicSharedMemorySize, tk_lds);
    topk_kernel<<<BATCH * NB, 256, tk_lds, stream>>>(qc, kc, top4);

    const int at_lds = 33792 * 2;                               // 67584 B -> 2 WGs/CU
    hipFuncSetAttribute((const void*)attn_kernel, hipFuncAttributeMaxDynamicSharedMemorySize, at_lds);
    attn_kernel<<<BATCH * NB, 256, at_lds, stream>>>(qf, kf, vtg, top4, out);
}